// Round 16
// baseline (170.414 us; speedup 1.0000x reference)
//
#include <hip/hip_runtime.h>
#include <math.h>

#define B_SIZE 8192
#define NVERT 778
#define NP 135
#define NEC 416
#define KS16 16

// ---- workspace layout (floats) ----
#define OFF_JK    0         // 48
#define OFF_C1    64        // 336  (21 x 16)
#define OFF_C0    400       // 1008 (21 x 48)
#define OFF_P2    1408      // 21*135*48 = 136080
#define OFF_PP    137488    // 16*416*336 (pfT/AT no longer exist; region free)
#define WS_END    2373904

__device__ inline void quat2mat_dev(float qw, float qx, float qy, float qz, float* R) {
  float n = sqrtf(qw*qw + qx*qx + qy*qy + qz*qz);
  float w = qw/n, x = qx/n, y = qy/n, z = qz/n;
  float w2=w*w, x2=x*x, y2=y*y, z2=z*z;
  float wx=w*x, wy=w*y, wz=w*z, xy=x*y, xz=x*z, yz=y*z;
  R[0]=w2+x2-y2-z2; R[1]=2.f*xy-2.f*wz; R[2]=2.f*wy+2.f*xz;
  R[3]=2.f*wz+2.f*xy; R[4]=w2-x2+y2-z2; R[5]=2.f*yz-2.f*wx;
  R[6]=2.f*xz-2.f*wy; R[7]=2.f*wx+2.f*yz; R[8]=w2-x2-y2+z2;
}

__device__ inline void rodrigues_dev(float tx, float ty, float tz, float* R) {
  float ax = tx + 1e-8f, ay = ty + 1e-8f, az = tz + 1e-8f;
  float angle = sqrtf(ax*ax + ay*ay + az*az);
  float nx = tx/angle, ny = ty/angle, nz = tz/angle;
  float half = 0.5f*angle;
  float cw = cosf(half), sw = sinf(half);
  quat2mat_dev(cw, sw*nx, sw*ny, sw*nz, R);
}

// kA: blocks 0..415 = single-chunk GEMM partials; 416..431 = Jk[j] regression. (proven)
__global__ __launch_bounds__(256) void kA(const float* __restrict__ J_regressor,
                                          const float* __restrict__ weights,
                                          const float* __restrict__ posedirs,
                                          const float* __restrict__ user_shape,
                                          const float* __restrict__ v_template,
                                          const float* __restrict__ shapedirs,
                                          float* __restrict__ ws) {
  int tid = threadIdx.x;
  int bid = blockIdx.x;

  if (bid >= 416) {
    int j = bid - 416;
    __shared__ float red[3*256];
    __shared__ float ush[10];
    if (tid < 10) ush[tid] = user_shape[tid];
    __syncthreads();
    float p0 = 0.f, p1 = 0.f, p2 = 0.f;
    for (int v = tid; v < NVERT; v += 256) {
      float jr = J_regressor[v*21 + j];
      #pragma unroll
      for (int c = 0; c < 3; ++c) {
        int e = 3*v + c;
        float t = v_template[e];
        #pragma unroll
        for (int s = 0; s < 10; ++s) t += ush[s]*shapedirs[s*2334 + e];
        float val = jr * t;
        if (c == 0) p0 += val; else if (c == 1) p1 += val; else p2 += val;
      }
    }
    red[0*256+tid] = p0; red[1*256+tid] = p1; red[2*256+tid] = p2;
    __syncthreads();
    for (int s = 128; s > 0; s >>= 1) {
      if (tid < s) {
        red[0*256+tid] += red[0*256+tid+s];
        red[1*256+tid] += red[1*256+tid+s];
        red[2*256+tid] += red[2*256+tid+s];
      }
      __syncthreads();
    }
    if (tid < 3) ws[OFF_JK + j*3 + tid] = red[tid*256];
    return;
  }

  __shared__ float sJR[49*21];
  __shared__ float sW [49*16];
  __shared__ float sB [64*16];
  __shared__ float ush[10];
  if (tid < 10) ush[tid] = user_shape[tid];
  int ng = bid % 26;
  int ks = bid / 26;
  int vbeg = ks*49;
  int kt = min(NVERT - vbeg, 49);
  __syncthreads();
  for (int idx = tid; idx < kt*21; idx += 256) sJR[idx] = J_regressor[vbeg*21 + idx];
  for (int idx = tid; idx < kt*16; idx += 256) sW[idx]  = weights[vbeg*16 + idx];
  for (int idx = tid; idx < 16*64; idx += 256) {
    int s = idx >> 6, iv = idx & 63;
    if (iv < kt) {
      int ec = ng*16 + s;
      float val;
      if (ec > 408) val = 0.f;
      else if (ec == 408) val = 1.f;
      else {
        int c = ec / 136, pp = ec - c*136;
        int e = 3*(vbeg+iv) + c;
        if (pp == 135) {
          float t = v_template[e];
          #pragma unroll
          for (int s0 = 0; s0 < 10; ++s0) t += ush[s0]*shapedirs[s0*2334 + e];
          val = t;
        } else {
          val = posedirs[pp*2334 + e];
        }
      }
      sB[iv*16 + s] = val;
    }
  }
  __syncthreads();
  if (tid < 168) {
    int cg2 = (tid < 84) ? 0 : 1;
    int r4  = (tid < 84) ? tid : tid - 84;
    int q2 = 4*r4;
    int j2 = q2 >> 4;
    int jb = q2 & 15;
    float acc[4][8];
    #pragma unroll
    for (int r = 0; r < 4; ++r)
      #pragma unroll
      for (int s = 0; s < 8; ++s) acc[r][s] = 0.f;
    for (int i = 0; i < kt; ++i) {
      float jr = sJR[i*21 + j2];
      float4 w4 = *(const float4*)&sW[i*16 + jb];
      float4 b0 = *(const float4*)&sB[i*16 + cg2*8];
      float4 b1 = *(const float4*)&sB[i*16 + cg2*8 + 4];
      float wv[4] = {w4.x, w4.y, w4.z, w4.w};
      #pragma unroll
      for (int r = 0; r < 4; ++r) {
        float s2 = jr * wv[r];
        acc[r][0] += s2*b0.x; acc[r][1] += s2*b0.y;
        acc[r][2] += s2*b0.z; acc[r][3] += s2*b0.w;
        acc[r][4] += s2*b1.x; acc[r][5] += s2*b1.y;
        acc[r][6] += s2*b1.z; acc[r][7] += s2*b1.w;
      }
    }
    float* Pp = ws + OFF_PP + (size_t)ks*NEC*336;
    #pragma unroll
    for (int s = 0; s < 8; ++s) {
      int ec = ng*16 + cg2*8 + s;
      float4 v4 = make_float4(acc[0][s], acc[1][s], acc[2][s], acc[3][s]);
      *(float4*)&Pp[ec*336 + q2] = v4;
    }
  }
}

// kR: float4-wide 16-way reduce -> P2/C0/C1. 137 blocks x 256. (proven)
__global__ void kR(float* __restrict__ ws) {
  int idx = blockIdx.x*256 + threadIdx.x;
  if (idx >= 416*84) return;
  int ec = idx / 84, q4 = idx - ec*84;
  const float* Pp = ws + OFF_PP;
  float4 s = make_float4(0.f, 0.f, 0.f, 0.f);
  #pragma unroll
  for (int ks = 0; ks < KS16; ++ks) {
    float4 v = *(const float4*)&Pp[(size_t)ks*NEC*336 + ec*336 + 4*q4];
    s.x += v.x; s.y += v.y; s.z += v.z; s.w += v.w;
  }
  float sv[4] = {s.x, s.y, s.z, s.w};
  #pragma unroll
  for (int r = 0; r < 4; ++r) {
    int q2 = 4*q4 + r;
    int jj2 = q2 >> 4, jj = q2 & 15;
    if (ec < 408) {
      int c = ec / 136, pp = ec - c*136;
      if (pp < 135) ws[OFF_P2 + (size_t)(jj2*135 + pp)*48 + jj*3 + c] = sv[r];
      else          ws[OFF_C0 + jj2*48 + jj*3 + c] = sv[r];
    } else if (ec == 408) {
      ws[OFF_C1 + jj2*16 + jj] = sv[r];
    }
  }
}

// k5f: fully fused pose + M-GEMM + contraction. Round-6 logic (correctness-proven)
// with round-15's VMEM P2 path (LDS-laundered offset -> global_load_dwordx4;
// avoids round-6's scalar-load degeneration). pfT/AT never materialized:
// the only per-iteration loads are L1-resident P2 rows.
__global__ __launch_bounds__(256) void k5f(const float* __restrict__ theta,
                                           const float* __restrict__ delta_quat,
                                           const float* __restrict__ init_quat,
                                           const float* __restrict__ init_trans,
                                           const float* __restrict__ ws,
                                           float* __restrict__ out) {
  __shared__ float s_jk[48], s_rel[48];
  __shared__ int s_voff[1];
  int g = blockIdx.x;
  int xcd = g & 7, k = g >> 3;
  int br  = ((k & 3) << 3) | xcd;
  int j2  = k >> 2;
  int tid = threadIdx.x;
  int b   = br*256 + tid;

  if (tid == 0) s_voff[0] = j2*135*12;   // float4 offset of this block's P2 slice
  if (tid < 48) {
    float v = ws[OFF_JK + tid];
    s_jk[tid] = v;
    int j = tid/3, c = tid - j*3;
    float r;
    if (j == 0) r = v;
    else {
      int par = (((j-1) % 3) == 0) ? 0 : (j-1);
      r = v - ws[OFF_JK + par*3 + c];
    }
    s_rel[tid] = r;
  }
  __syncthreads();
  int voff = s_voff[0];                  // compiler sees divergent -> VMEM addressing

  // m init = C0[j2]
  float m[48];
  {
    const float* C0r = ws + OFF_C0 + j2*48;
    #pragma unroll
    for (int i = 0; i < 48; ++i) m[i] = C0r[i];
  }

  const float* th = theta + (size_t)b*45;
  const float4* P24 = (const float4*)(ws + OFF_P2) + voff;

  // ---- pass 1: fold pose features into m against P2 (VMEM float4 loads) ----
  for (int i = 0; i < 15; ++i) {
    float R[9];
    rodrigues_dev(th[3*i+0], th[3*i+1], th[3*i+2], R);
    float pf[9] = {R[0]-1.f, R[1], R[2], R[3], R[4]-1.f, R[5], R[6], R[7], R[8]-1.f};
    const float4* Pi = P24 + i*9*12;
    #pragma unroll
    for (int r = 0; r < 9; ++r) {
      float s = pf[r];
      const float4* Pr = Pi + r*12;
      #pragma unroll
      for (int kk = 0; kk < 12; ++kk) {
        float4 pv = Pr[kk];
        m[4*kk+0] += s*pv.x; m[4*kk+1] += s*pv.y;
        m[4*kk+2] += s*pv.z; m[4*kk+3] += s*pv.w;
      }
    }
  }

  // ---- pass 2: chain walk + contraction (round-6 verified math) ----
  const float* c1p = ws + OFF_C1 + j2*16;
  float o0 = 0.f, o1 = 0.f, o2 = 0.f;

  float Gr[12];
  {
    float w1=delta_quat[b*4+0], x1=delta_quat[b*4+1], y1=delta_quat[b*4+2], z1=delta_quat[b*4+3];
    float w2=init_quat[0], x2=init_quat[1], y2=init_quat[2], z2=init_quat[3];
    float qw = w1*w2 - x1*x2 - y1*y2 - z1*z2;
    float qx = w1*x2 + x1*w2 + y1*z2 - z1*y2;
    float qy = w1*y2 - x1*z2 + y1*w2 + z1*x2;
    float qz = w1*z2 + x1*y2 - y1*x2 + z1*w2;
    quat2mat_dev(qw, qx, qy, qz, Gr);
    Gr[9] = s_rel[0]; Gr[10] = s_rel[1]; Gr[11] = s_rel[2];
  }
  {
    float c1 = c1p[0];
    float t0 = m[0] - c1*s_jk[0], t1 = m[1] - c1*s_jk[1], t2 = m[2] - c1*s_jk[2];
    o0 += Gr[0]*t0 + Gr[1]*t1 + Gr[2]*t2 + Gr[9]*c1;
    o1 += Gr[3]*t0 + Gr[4]*t1 + Gr[5]*t2 + Gr[10]*c1;
    o2 += Gr[6]*t0 + Gr[7]*t1 + Gr[8]*t2 + Gr[11]*c1;
  }
  for (int u = 0; u < 5; ++u) {
    float G[12];
    #pragma unroll
    for (int q = 0; q < 12; ++q) G[q] = Gr[q];
    for (int ms = 0; ms < 3; ++ms) {
      int j = 3*u + 1 + ms;
      int i = j - 1;
      float R[9];
      rodrigues_dev(th[3*i+0], th[3*i+1], th[3*i+2], R);
      float nG[12];
      const float* rj = s_rel + j*3;
      #pragma unroll
      for (int r3 = 0; r3 < 3; ++r3) {
        float a0 = G[r3*3+0], a1 = G[r3*3+1], a2 = G[r3*3+2];
        nG[r3*3+0] = a0*R[0] + a1*R[3] + a2*R[6];
        nG[r3*3+1] = a0*R[1] + a1*R[4] + a2*R[7];
        nG[r3*3+2] = a0*R[2] + a1*R[5] + a2*R[8];
        nG[9+r3]   = G[9+r3] + a0*rj[0] + a1*rj[1] + a2*rj[2];
      }
      #pragma unroll
      for (int q = 0; q < 12; ++q) G[q] = nG[q];
      float c1 = c1p[j];
      const float* jk3 = s_jk + j*3;
      float m0 = m[3*j+0], m1 = m[3*j+1], m2 = m[3*j+2];
      float t0 = m0 - c1*jk3[0], t1 = m1 - c1*jk3[1], t2 = m2 - c1*jk3[2];
      o0 += G[0]*t0 + G[1]*t1 + G[2]*t2 + G[9]*c1;
      o1 += G[3]*t0 + G[4]*t1 + G[5]*t2 + G[10]*c1;
      o2 += G[6]*t0 + G[7]*t1 + G[8]*t2 + G[11]*c1;
    }
  }
  size_t ob = ((size_t)b*21 + j2)*3;
  out[ob+0] = o0 + init_trans[b*3+0];
  out[ob+1] = o1 + init_trans[b*3+1];
  out[ob+2] = o2 + init_trans[b*3+2];
}

extern "C" void kernel_launch(void* const* d_in, const int* in_sizes, int n_in,
                              void* d_out, int out_size, void* d_ws, size_t ws_size,
                              hipStream_t stream) {
  const float* theta       = (const float*)d_in[0];
  const float* delta_quat  = (const float*)d_in[1];
  const float* user_shape  = (const float*)d_in[2];
  const float* init_quat   = (const float*)d_in[3];
  const float* init_trans  = (const float*)d_in[4];
  const float* v_template  = (const float*)d_in[5];
  const float* shapedirs   = (const float*)d_in[6];
  const float* J_regressor = (const float*)d_in[7];
  const float* posedirs    = (const float*)d_in[8];
  const float* weights     = (const float*)d_in[9];
  float* out = (float*)d_out;
  float* ws  = (float*)d_ws;

  kA<<<432, 256, 0, stream>>>(J_regressor, weights, posedirs,
                              user_shape, v_template, shapedirs, ws);
  kR<<<137, 256, 0, stream>>>(ws);
  k5f<<<672, 256, 0, stream>>>(theta, delta_quat, init_quat, init_trans, ws, out);
}

// Round 17
// 166.253 us; speedup vs baseline: 1.0250x; 1.0250x over previous
//
#include <hip/hip_runtime.h>
#include <math.h>

#define B_SIZE 8192
#define NVERT 778
#define NP 135
#define NEC 416
#define KS16 16

// ---- workspace layout (floats) ----
#define OFF_JK    0         // 48
#define OFF_C1    64        // 336  (21 x 16)
#define OFF_C0    400       // 1008 (21 x 48)
#define OFF_P2    1408      // 21*135*48 = 136080
#define OFF_PP    137488    // 16*416*336
#define WS_END    2373904

__device__ inline void quat2mat_dev(float qw, float qx, float qy, float qz, float* R) {
  float n = sqrtf(qw*qw + qx*qx + qy*qy + qz*qz);
  float w = qw/n, x = qx/n, y = qy/n, z = qz/n;
  float w2=w*w, x2=x*x, y2=y*y, z2=z*z;
  float wx=w*x, wy=w*y, wz=w*z, xy=x*y, xz=x*z, yz=y*z;
  R[0]=w2+x2-y2-z2; R[1]=2.f*xy-2.f*wz; R[2]=2.f*wy+2.f*xz;
  R[3]=2.f*wz+2.f*xy; R[4]=w2-x2+y2-z2; R[5]=2.f*yz-2.f*wx;
  R[6]=2.f*xz-2.f*wy; R[7]=2.f*wx+2.f*yz; R[8]=w2-x2-y2+z2;
}

__device__ inline void rodrigues_dev(float tx, float ty, float tz, float* R) {
  float ax = tx + 1e-8f, ay = ty + 1e-8f, az = tz + 1e-8f;
  float angle = sqrtf(ax*ax + ay*ay + az*az);
  float nx = tx/angle, ny = ty/angle, nz = tz/angle;
  float half = 0.5f*angle;
  float cw = cosf(half), sw = sinf(half);
  quat2mat_dev(cw, sw*nx, sw*ny, sw*nz, R);
}

// kA: blocks 0..415 = single-chunk GEMM partials; 416..431 = Jk[j] regression. (proven)
__global__ __launch_bounds__(256) void kA(const float* __restrict__ J_regressor,
                                          const float* __restrict__ weights,
                                          const float* __restrict__ posedirs,
                                          const float* __restrict__ user_shape,
                                          const float* __restrict__ v_template,
                                          const float* __restrict__ shapedirs,
                                          float* __restrict__ ws) {
  int tid = threadIdx.x;
  int bid = blockIdx.x;

  if (bid >= 416) {
    int j = bid - 416;
    __shared__ float red[3*256];
    __shared__ float ush[10];
    if (tid < 10) ush[tid] = user_shape[tid];
    __syncthreads();
    float p0 = 0.f, p1 = 0.f, p2 = 0.f;
    for (int v = tid; v < NVERT; v += 256) {
      float jr = J_regressor[v*21 + j];
      #pragma unroll
      for (int c = 0; c < 3; ++c) {
        int e = 3*v + c;
        float t = v_template[e];
        #pragma unroll
        for (int s = 0; s < 10; ++s) t += ush[s]*shapedirs[s*2334 + e];
        float val = jr * t;
        if (c == 0) p0 += val; else if (c == 1) p1 += val; else p2 += val;
      }
    }
    red[0*256+tid] = p0; red[1*256+tid] = p1; red[2*256+tid] = p2;
    __syncthreads();
    for (int s = 128; s > 0; s >>= 1) {
      if (tid < s) {
        red[0*256+tid] += red[0*256+tid+s];
        red[1*256+tid] += red[1*256+tid+s];
        red[2*256+tid] += red[2*256+tid+s];
      }
      __syncthreads();
    }
    if (tid < 3) ws[OFF_JK + j*3 + tid] = red[tid*256];
    return;
  }

  __shared__ float sJR[49*21];
  __shared__ float sW [49*16];
  __shared__ float sB [64*16];
  __shared__ float ush[10];
  if (tid < 10) ush[tid] = user_shape[tid];
  int ng = bid % 26;
  int ks = bid / 26;
  int vbeg = ks*49;
  int kt = min(NVERT - vbeg, 49);
  __syncthreads();
  for (int idx = tid; idx < kt*21; idx += 256) sJR[idx] = J_regressor[vbeg*21 + idx];
  for (int idx = tid; idx < kt*16; idx += 256) sW[idx]  = weights[vbeg*16 + idx];
  for (int idx = tid; idx < 16*64; idx += 256) {
    int s = idx >> 6, iv = idx & 63;
    if (iv < kt) {
      int ec = ng*16 + s;
      float val;
      if (ec > 408) val = 0.f;
      else if (ec == 408) val = 1.f;
      else {
        int c = ec / 136, pp = ec - c*136;
        int e = 3*(vbeg+iv) + c;
        if (pp == 135) {
          float t = v_template[e];
          #pragma unroll
          for (int s0 = 0; s0 < 10; ++s0) t += ush[s0]*shapedirs[s0*2334 + e];
          val = t;
        } else {
          val = posedirs[pp*2334 + e];
        }
      }
      sB[iv*16 + s] = val;
    }
  }
  __syncthreads();
  if (tid < 168) {
    int cg2 = (tid < 84) ? 0 : 1;
    int r4  = (tid < 84) ? tid : tid - 84;
    int q2 = 4*r4;
    int j2 = q2 >> 4;
    int jb = q2 & 15;
    float acc[4][8];
    #pragma unroll
    for (int r = 0; r < 4; ++r)
      #pragma unroll
      for (int s = 0; s < 8; ++s) acc[r][s] = 0.f;
    for (int i = 0; i < kt; ++i) {
      float jr = sJR[i*21 + j2];
      float4 w4 = *(const float4*)&sW[i*16 + jb];
      float4 b0 = *(const float4*)&sB[i*16 + cg2*8];
      float4 b1 = *(const float4*)&sB[i*16 + cg2*8 + 4];
      float wv[4] = {w4.x, w4.y, w4.z, w4.w};
      #pragma unroll
      for (int r = 0; r < 4; ++r) {
        float s2 = jr * wv[r];
        acc[r][0] += s2*b0.x; acc[r][1] += s2*b0.y;
        acc[r][2] += s2*b0.z; acc[r][3] += s2*b0.w;
        acc[r][4] += s2*b1.x; acc[r][5] += s2*b1.y;
        acc[r][6] += s2*b1.z; acc[r][7] += s2*b1.w;
      }
    }
    float* Pp = ws + OFF_PP + (size_t)ks*NEC*336;
    #pragma unroll
    for (int s = 0; s < 8; ++s) {
      int ec = ng*16 + cg2*8 + s;
      float4 v4 = make_float4(acc[0][s], acc[1][s], acc[2][s], acc[3][s]);
      *(float4*)&Pp[ec*336 + q2] = v4;
    }
  }
}

// kR: float4-wide 16-way reduce -> P2/C0/C1. 137 blocks x 256. (proven)
__global__ void kR(float* __restrict__ ws) {
  int idx = blockIdx.x*256 + threadIdx.x;
  if (idx >= 416*84) return;
  int ec = idx / 84, q4 = idx - ec*84;
  const float* Pp = ws + OFF_PP;
  float4 s = make_float4(0.f, 0.f, 0.f, 0.f);
  #pragma unroll
  for (int ks = 0; ks < KS16; ++ks) {
    float4 v = *(const float4*)&Pp[(size_t)ks*NEC*336 + ec*336 + 4*q4];
    s.x += v.x; s.y += v.y; s.z += v.z; s.w += v.w;
  }
  float sv[4] = {s.x, s.y, s.z, s.w};
  #pragma unroll
  for (int r = 0; r < 4; ++r) {
    int q2 = 4*q4 + r;
    int jj2 = q2 >> 4, jj = q2 & 15;
    if (ec < 408) {
      int c = ec / 136, pp = ec - c*136;
      if (pp < 135) ws[OFF_P2 + (size_t)(jj2*135 + pp)*48 + jj*3 + c] = sv[r];
      else          ws[OFF_C0 + jj2*48 + jj*3 + c] = sv[r];
    } else if (ec == 408) {
      ws[OFF_C1 + jj2*16 + jj] = sv[r];
    }
  }
}

// k5f v2: fused pose + M-GEMM + contraction.
// Pass 1: m[48] in REGISTERS (constant indices only), P2 via VMEM (LDS-laundered offset).
// Then m spilled ONCE to LDS (thread-owned slice, stride 48 = 2-way bank alias = free).
// Pass 2: dynamic m[3*j] reads hit LDS, not scratch (round-16's 61 MB spill fix).
__global__ __launch_bounds__(256) void k5f(const float* __restrict__ theta,
                                           const float* __restrict__ delta_quat,
                                           const float* __restrict__ init_quat,
                                           const float* __restrict__ init_trans,
                                           const float* __restrict__ ws,
                                           float* __restrict__ out) {
  __shared__ float sM[256*48];    // 49152 B: per-thread m slice
  __shared__ float s_jk[48], s_rel[48];
  __shared__ int s_voff[1];
  int g = blockIdx.x;
  int xcd = g & 7, k = g >> 3;
  int br  = ((k & 3) << 3) | xcd;
  int j2  = k >> 2;
  int tid = threadIdx.x;
  int b   = br*256 + tid;

  if (tid == 0) s_voff[0] = j2*135*12;
  if (tid < 48) {
    float v = ws[OFF_JK + tid];
    s_jk[tid] = v;
    int j = tid/3, c = tid - j*3;
    float r;
    if (j == 0) r = v;
    else {
      int par = (((j-1) % 3) == 0) ? 0 : (j-1);
      r = v - ws[OFF_JK + par*3 + c];
    }
    s_rel[tid] = r;
  }
  __syncthreads();
  int voff = s_voff[0];           // divergent in compiler's view -> VMEM addressing

  // ---- pass 1: m in registers, constant indices ----
  float m[48];
  {
    const float* C0r = ws + OFF_C0 + j2*48;
    #pragma unroll
    for (int i = 0; i < 48; ++i) m[i] = C0r[i];
  }
  const float* th = theta + (size_t)b*45;
  const float4* P24 = (const float4*)(ws + OFF_P2) + voff;

  for (int i = 0; i < 15; ++i) {
    float R[9];
    rodrigues_dev(th[3*i+0], th[3*i+1], th[3*i+2], R);
    float pf[9] = {R[0]-1.f, R[1], R[2], R[3], R[4]-1.f, R[5], R[6], R[7], R[8]-1.f};
    const float4* Pi = P24 + i*9*12;
    #pragma unroll
    for (int r = 0; r < 9; ++r) {
      float s = pf[r];
      const float4* Pr = Pi + r*12;
      #pragma unroll
      for (int kk = 0; kk < 12; ++kk) {
        float4 pv = Pr[kk];
        m[4*kk+0] += s*pv.x; m[4*kk+1] += s*pv.y;
        m[4*kk+2] += s*pv.z; m[4*kk+3] += s*pv.w;
      }
    }
  }

  // spill m once to LDS (constant-indexed stores; stride 48 floats -> free 2-way alias)
  {
    float* mr = sM + tid*48;
    #pragma unroll
    for (int i = 0; i < 48; ++i) mr[i] = m[i];
  }
  // no barrier needed: each thread reads only its own slice

  // ---- pass 2: chain walk + contraction; m read from LDS (dynamic index OK) ----
  const float* mr = sM + tid*48;
  const float* c1p = ws + OFF_C1 + j2*16;
  float o0 = 0.f, o1 = 0.f, o2 = 0.f;

  float Gr[12];
  {
    float w1=delta_quat[b*4+0], x1=delta_quat[b*4+1], y1=delta_quat[b*4+2], z1=delta_quat[b*4+3];
    float w2=init_quat[0], x2=init_quat[1], y2=init_quat[2], z2=init_quat[3];
    float qw = w1*w2 - x1*x2 - y1*y2 - z1*z2;
    float qx = w1*x2 + x1*w2 + y1*z2 - z1*y2;
    float qy = w1*y2 - x1*z2 + y1*w2 + z1*x2;
    float qz = w1*z2 + x1*y2 - y1*x2 + z1*w2;
    quat2mat_dev(qw, qx, qy, qz, Gr);
    Gr[9] = s_rel[0]; Gr[10] = s_rel[1]; Gr[11] = s_rel[2];
  }
  {
    float c1 = c1p[0];
    float t0 = mr[0] - c1*s_jk[0], t1 = mr[1] - c1*s_jk[1], t2 = mr[2] - c1*s_jk[2];
    o0 += Gr[0]*t0 + Gr[1]*t1 + Gr[2]*t2 + Gr[9]*c1;
    o1 += Gr[3]*t0 + Gr[4]*t1 + Gr[5]*t2 + Gr[10]*c1;
    o2 += Gr[6]*t0 + Gr[7]*t1 + Gr[8]*t2 + Gr[11]*c1;
  }
  for (int u = 0; u < 5; ++u) {
    float G[12];
    #pragma unroll
    for (int q = 0; q < 12; ++q) G[q] = Gr[q];
    for (int ms = 0; ms < 3; ++ms) {
      int j = 3*u + 1 + ms;
      int i = j - 1;
      float R[9];
      rodrigues_dev(th[3*i+0], th[3*i+1], th[3*i+2], R);
      float nG[12];
      const float* rj = s_rel + j*3;
      #pragma unroll
      for (int r3 = 0; r3 < 3; ++r3) {
        float a0 = G[r3*3+0], a1 = G[r3*3+1], a2 = G[r3*3+2];
        nG[r3*3+0] = a0*R[0] + a1*R[3] + a2*R[6];
        nG[r3*3+1] = a0*R[1] + a1*R[4] + a2*R[7];
        nG[r3*3+2] = a0*R[2] + a1*R[5] + a2*R[8];
        nG[9+r3]   = G[9+r3] + a0*rj[0] + a1*rj[1] + a2*rj[2];
      }
      #pragma unroll
      for (int q = 0; q < 12; ++q) G[q] = nG[q];
      float c1 = c1p[j];
      const float* jk3 = s_jk + j*3;
      float m0 = mr[3*j+0], m1 = mr[3*j+1], m2 = mr[3*j+2];
      float t0 = m0 - c1*jk3[0], t1 = m1 - c1*jk3[1], t2 = m2 - c1*jk3[2];
      o0 += G[0]*t0 + G[1]*t1 + G[2]*t2 + G[9]*c1;
      o1 += G[3]*t0 + G[4]*t1 + G[5]*t2 + G[10]*c1;
      o2 += G[6]*t0 + G[7]*t1 + G[8]*t2 + G[11]*c1;
    }
  }
  size_t ob = ((size_t)b*21 + j2)*3;
  out[ob+0] = o0 + init_trans[b*3+0];
  out[ob+1] = o1 + init_trans[b*3+1];
  out[ob+2] = o2 + init_trans[b*3+2];
}

extern "C" void kernel_launch(void* const* d_in, const int* in_sizes, int n_in,
                              void* d_out, int out_size, void* d_ws, size_t ws_size,
                              hipStream_t stream) {
  const float* theta       = (const float*)d_in[0];
  const float* delta_quat  = (const float*)d_in[1];
  const float* user_shape  = (const float*)d_in[2];
  const float* init_quat   = (const float*)d_in[3];
  const float* init_trans  = (const float*)d_in[4];
  const float* v_template  = (const float*)d_in[5];
  const float* shapedirs   = (const float*)d_in[6];
  const float* J_regressor = (const float*)d_in[7];
  const float* posedirs    = (const float*)d_in[8];
  const float* weights     = (const float*)d_in[9];
  float* out = (float*)d_out;
  float* ws  = (float*)d_ws;

  kA<<<432, 256, 0, stream>>>(J_regressor, weights, posedirs,
                              user_shape, v_template, shapedirs, ws);
  kR<<<137, 256, 0, stream>>>(ws);
  k5f<<<672, 256, 0, stream>>>(theta, delta_quat, init_quat, init_trans, ws, out);
}

// Round 18
// 166.012 us; speedup vs baseline: 1.0265x; 1.0015x over previous
//
#include <hip/hip_runtime.h>
#include <math.h>

#define B_SIZE 8192
#define NVERT 778
#define NP 135
#define NEC 416
#define KS16 16
#define MSTRIDE 49   // odd float stride: lane l -> bank (17l+i)%32, all 32 banks, 2 lanes/bank = free

// ---- workspace layout (floats) ----
#define OFF_JK    0         // 48
#define OFF_C1    64        // 336  (21 x 16)
#define OFF_C0    400       // 1008 (21 x 48)
#define OFF_P2    1408      // 21*135*48 = 136080
#define OFF_PP    137488    // 16*416*336
#define WS_END    2373904

__device__ inline void quat2mat_dev(float qw, float qx, float qy, float qz, float* R) {
  float n = sqrtf(qw*qw + qx*qx + qy*qy + qz*qz);
  float w = qw/n, x = qx/n, y = qy/n, z = qz/n;
  float w2=w*w, x2=x*x, y2=y*y, z2=z*z;
  float wx=w*x, wy=w*y, wz=w*z, xy=x*y, xz=x*z, yz=y*z;
  R[0]=w2+x2-y2-z2; R[1]=2.f*xy-2.f*wz; R[2]=2.f*wy+2.f*xz;
  R[3]=2.f*wz+2.f*xy; R[4]=w2-x2+y2-z2; R[5]=2.f*yz-2.f*wx;
  R[6]=2.f*xz-2.f*wy; R[7]=2.f*wx+2.f*yz; R[8]=w2-x2-y2+z2;
}

__device__ inline void rodrigues_dev(float tx, float ty, float tz, float* R) {
  float ax = tx + 1e-8f, ay = ty + 1e-8f, az = tz + 1e-8f;
  float angle = sqrtf(ax*ax + ay*ay + az*az);
  float nx = tx/angle, ny = ty/angle, nz = tz/angle;
  float half = 0.5f*angle;
  float cw = cosf(half), sw = sinf(half);
  quat2mat_dev(cw, sw*nx, sw*ny, sw*nz, R);
}

// kA: blocks 0..415 = single-chunk GEMM partials; 416..431 = Jk[j] regression. (proven)
__global__ __launch_bounds__(256) void kA(const float* __restrict__ J_regressor,
                                          const float* __restrict__ weights,
                                          const float* __restrict__ posedirs,
                                          const float* __restrict__ user_shape,
                                          const float* __restrict__ v_template,
                                          const float* __restrict__ shapedirs,
                                          float* __restrict__ ws) {
  int tid = threadIdx.x;
  int bid = blockIdx.x;

  if (bid >= 416) {
    int j = bid - 416;
    __shared__ float red[3*256];
    __shared__ float ush[10];
    if (tid < 10) ush[tid] = user_shape[tid];
    __syncthreads();
    float p0 = 0.f, p1 = 0.f, p2 = 0.f;
    for (int v = tid; v < NVERT; v += 256) {
      float jr = J_regressor[v*21 + j];
      #pragma unroll
      for (int c = 0; c < 3; ++c) {
        int e = 3*v + c;
        float t = v_template[e];
        #pragma unroll
        for (int s = 0; s < 10; ++s) t += ush[s]*shapedirs[s*2334 + e];
        float val = jr * t;
        if (c == 0) p0 += val; else if (c == 1) p1 += val; else p2 += val;
      }
    }
    red[0*256+tid] = p0; red[1*256+tid] = p1; red[2*256+tid] = p2;
    __syncthreads();
    for (int s = 128; s > 0; s >>= 1) {
      if (tid < s) {
        red[0*256+tid] += red[0*256+tid+s];
        red[1*256+tid] += red[1*256+tid+s];
        red[2*256+tid] += red[2*256+tid+s];
      }
      __syncthreads();
    }
    if (tid < 3) ws[OFF_JK + j*3 + tid] = red[tid*256];
    return;
  }

  __shared__ float sJR[49*21];
  __shared__ float sW [49*16];
  __shared__ float sB [64*16];
  __shared__ float ush[10];
  if (tid < 10) ush[tid] = user_shape[tid];
  int ng = bid % 26;
  int ks = bid / 26;
  int vbeg = ks*49;
  int kt = min(NVERT - vbeg, 49);
  __syncthreads();
  for (int idx = tid; idx < kt*21; idx += 256) sJR[idx] = J_regressor[vbeg*21 + idx];
  for (int idx = tid; idx < kt*16; idx += 256) sW[idx]  = weights[vbeg*16 + idx];
  for (int idx = tid; idx < 16*64; idx += 256) {
    int s = idx >> 6, iv = idx & 63;
    if (iv < kt) {
      int ec = ng*16 + s;
      float val;
      if (ec > 408) val = 0.f;
      else if (ec == 408) val = 1.f;
      else {
        int c = ec / 136, pp = ec - c*136;
        int e = 3*(vbeg+iv) + c;
        if (pp == 135) {
          float t = v_template[e];
          #pragma unroll
          for (int s0 = 0; s0 < 10; ++s0) t += ush[s0]*shapedirs[s0*2334 + e];
          val = t;
        } else {
          val = posedirs[pp*2334 + e];
        }
      }
      sB[iv*16 + s] = val;
    }
  }
  __syncthreads();
  if (tid < 168) {
    int cg2 = (tid < 84) ? 0 : 1;
    int r4  = (tid < 84) ? tid : tid - 84;
    int q2 = 4*r4;
    int j2 = q2 >> 4;
    int jb = q2 & 15;
    float acc[4][8];
    #pragma unroll
    for (int r = 0; r < 4; ++r)
      #pragma unroll
      for (int s = 0; s < 8; ++s) acc[r][s] = 0.f;
    for (int i = 0; i < kt; ++i) {
      float jr = sJR[i*21 + j2];
      float4 w4 = *(const float4*)&sW[i*16 + jb];
      float4 b0 = *(const float4*)&sB[i*16 + cg2*8];
      float4 b1 = *(const float4*)&sB[i*16 + cg2*8 + 4];
      float wv[4] = {w4.x, w4.y, w4.z, w4.w};
      #pragma unroll
      for (int r = 0; r < 4; ++r) {
        float s2 = jr * wv[r];
        acc[r][0] += s2*b0.x; acc[r][1] += s2*b0.y;
        acc[r][2] += s2*b0.z; acc[r][3] += s2*b0.w;
        acc[r][4] += s2*b1.x; acc[r][5] += s2*b1.y;
        acc[r][6] += s2*b1.z; acc[r][7] += s2*b1.w;
      }
    }
    float* Pp = ws + OFF_PP + (size_t)ks*NEC*336;
    #pragma unroll
    for (int s = 0; s < 8; ++s) {
      int ec = ng*16 + cg2*8 + s;
      float4 v4 = make_float4(acc[0][s], acc[1][s], acc[2][s], acc[3][s]);
      *(float4*)&Pp[ec*336 + q2] = v4;
    }
  }
}

// kR: float4-wide 16-way reduce -> P2/C0/C1. 137 blocks x 256. (proven)
__global__ void kR(float* __restrict__ ws) {
  int idx = blockIdx.x*256 + threadIdx.x;
  if (idx >= 416*84) return;
  int ec = idx / 84, q4 = idx - ec*84;
  const float* Pp = ws + OFF_PP;
  float4 s = make_float4(0.f, 0.f, 0.f, 0.f);
  #pragma unroll
  for (int ks = 0; ks < KS16; ++ks) {
    float4 v = *(const float4*)&Pp[(size_t)ks*NEC*336 + ec*336 + 4*q4];
    s.x += v.x; s.y += v.y; s.z += v.z; s.w += v.w;
  }
  float sv[4] = {s.x, s.y, s.z, s.w};
  #pragma unroll
  for (int r = 0; r < 4; ++r) {
    int q2 = 4*q4 + r;
    int jj2 = q2 >> 4, jj = q2 & 15;
    if (ec < 408) {
      int c = ec / 136, pp = ec - c*136;
      if (pp < 135) ws[OFF_P2 + (size_t)(jj2*135 + pp)*48 + jj*3 + c] = sv[r];
      else          ws[OFF_C0 + jj2*48 + jj*3 + c] = sv[r];
    } else if (ec == 408) {
      ws[OFF_C1 + jj2*16 + jj] = sv[r];
    }
  }
}

// k5f v3: fused pose + M-GEMM + contraction. Identical to v2 except the LDS m-slice
// stride is 49 floats (odd) -> lane l hits bank (17l+i)%32: all 32 banks, 2 lanes/bank,
// conflict-free (v2's stride 48 = 16 mod 32 put 32 lanes on 2 banks -> 4.47M conflicts).
__global__ __launch_bounds__(256) void k5f(const float* __restrict__ theta,
                                           const float* __restrict__ delta_quat,
                                           const float* __restrict__ init_quat,
                                           const float* __restrict__ init_trans,
                                           const float* __restrict__ ws,
                                           float* __restrict__ out) {
  __shared__ float sM[256*MSTRIDE];    // 50176 B, still 3 blocks/CU
  __shared__ float s_jk[48], s_rel[48];
  __shared__ int s_voff[1];
  int g = blockIdx.x;
  int xcd = g & 7, k = g >> 3;
  int br  = ((k & 3) << 3) | xcd;
  int j2  = k >> 2;
  int tid = threadIdx.x;
  int b   = br*256 + tid;

  if (tid == 0) s_voff[0] = j2*135*12;
  if (tid < 48) {
    float v = ws[OFF_JK + tid];
    s_jk[tid] = v;
    int j = tid/3, c = tid - j*3;
    float r;
    if (j == 0) r = v;
    else {
      int par = (((j-1) % 3) == 0) ? 0 : (j-1);
      r = v - ws[OFF_JK + par*3 + c];
    }
    s_rel[tid] = r;
  }
  __syncthreads();
  int voff = s_voff[0];           // divergent in compiler's view -> VMEM addressing

  // ---- pass 1: m in registers, constant indices ----
  float m[48];
  {
    const float* C0r = ws + OFF_C0 + j2*48;
    #pragma unroll
    for (int i = 0; i < 48; ++i) m[i] = C0r[i];
  }
  const float* th = theta + (size_t)b*45;
  const float4* P24 = (const float4*)(ws + OFF_P2) + voff;

  for (int i = 0; i < 15; ++i) {
    float R[9];
    rodrigues_dev(th[3*i+0], th[3*i+1], th[3*i+2], R);
    float pf[9] = {R[0]-1.f, R[1], R[2], R[3], R[4]-1.f, R[5], R[6], R[7], R[8]-1.f};
    const float4* Pi = P24 + i*9*12;
    #pragma unroll
    for (int r = 0; r < 9; ++r) {
      float s = pf[r];
      const float4* Pr = Pi + r*12;
      #pragma unroll
      for (int kk = 0; kk < 12; ++kk) {
        float4 pv = Pr[kk];
        m[4*kk+0] += s*pv.x; m[4*kk+1] += s*pv.y;
        m[4*kk+2] += s*pv.z; m[4*kk+3] += s*pv.w;
      }
    }
  }

  // spill m once to LDS (odd stride -> conflict-free)
  {
    float* mr = sM + tid*MSTRIDE;
    #pragma unroll
    for (int i = 0; i < 48; ++i) mr[i] = m[i];
  }
  // no barrier: each thread reads only its own slice

  // ---- pass 2: chain walk + contraction; m read from LDS ----
  const float* mr = sM + tid*MSTRIDE;
  const float* c1p = ws + OFF_C1 + j2*16;
  float o0 = 0.f, o1 = 0.f, o2 = 0.f;

  float Gr[12];
  {
    float w1=delta_quat[b*4+0], x1=delta_quat[b*4+1], y1=delta_quat[b*4+2], z1=delta_quat[b*4+3];
    float w2=init_quat[0], x2=init_quat[1], y2=init_quat[2], z2=init_quat[3];
    float qw = w1*w2 - x1*x2 - y1*y2 - z1*z2;
    float qx = w1*x2 + x1*w2 + y1*z2 - z1*y2;
    float qy = w1*y2 - x1*z2 + y1*w2 + z1*x2;
    float qz = w1*z2 + x1*y2 - y1*x2 + z1*w2;
    quat2mat_dev(qw, qx, qy, qz, Gr);
    Gr[9] = s_rel[0]; Gr[10] = s_rel[1]; Gr[11] = s_rel[2];
  }
  {
    float c1 = c1p[0];
    float t0 = mr[0] - c1*s_jk[0], t1 = mr[1] - c1*s_jk[1], t2 = mr[2] - c1*s_jk[2];
    o0 += Gr[0]*t0 + Gr[1]*t1 + Gr[2]*t2 + Gr[9]*c1;
    o1 += Gr[3]*t0 + Gr[4]*t1 + Gr[5]*t2 + Gr[10]*c1;
    o2 += Gr[6]*t0 + Gr[7]*t1 + Gr[8]*t2 + Gr[11]*c1;
  }
  for (int u = 0; u < 5; ++u) {
    float G[12];
    #pragma unroll
    for (int q = 0; q < 12; ++q) G[q] = Gr[q];
    for (int ms = 0; ms < 3; ++ms) {
      int j = 3*u + 1 + ms;
      int i = j - 1;
      float R[9];
      rodrigues_dev(th[3*i+0], th[3*i+1], th[3*i+2], R);
      float nG[12];
      const float* rj = s_rel + j*3;
      #pragma unroll
      for (int r3 = 0; r3 < 3; ++r3) {
        float a0 = G[r3*3+0], a1 = G[r3*3+1], a2 = G[r3*3+2];
        nG[r3*3+0] = a0*R[0] + a1*R[3] + a2*R[6];
        nG[r3*3+1] = a0*R[1] + a1*R[4] + a2*R[7];
        nG[r3*3+2] = a0*R[2] + a1*R[5] + a2*R[8];
        nG[9+r3]   = G[9+r3] + a0*rj[0] + a1*rj[1] + a2*rj[2];
      }
      #pragma unroll
      for (int q = 0; q < 12; ++q) G[q] = nG[q];
      float c1 = c1p[j];
      const float* jk3 = s_jk + j*3;
      float m0 = mr[3*j+0], m1 = mr[3*j+1], m2 = mr[3*j+2];
      float t0 = m0 - c1*jk3[0], t1 = m1 - c1*jk3[1], t2 = m2 - c1*jk3[2];
      o0 += G[0]*t0 + G[1]*t1 + G[2]*t2 + G[9]*c1;
      o1 += G[3]*t0 + G[4]*t1 + G[5]*t2 + G[10]*c1;
      o2 += G[6]*t0 + G[7]*t1 + G[8]*t2 + G[11]*c1;
    }
  }
  size_t ob = ((size_t)b*21 + j2)*3;
  out[ob+0] = o0 + init_trans[b*3+0];
  out[ob+1] = o1 + init_trans[b*3+1];
  out[ob+2] = o2 + init_trans[b*3+2];
}

extern "C" void kernel_launch(void* const* d_in, const int* in_sizes, int n_in,
                              void* d_out, int out_size, void* d_ws, size_t ws_size,
                              hipStream_t stream) {
  const float* theta       = (const float*)d_in[0];
  const float* delta_quat  = (const float*)d_in[1];
  const float* user_shape  = (const float*)d_in[2];
  const float* init_quat   = (const float*)d_in[3];
  const float* init_trans  = (const float*)d_in[4];
  const float* v_template  = (const float*)d_in[5];
  const float* shapedirs   = (const float*)d_in[6];
  const float* J_regressor = (const float*)d_in[7];
  const float* posedirs    = (const float*)d_in[8];
  const float* weights     = (const float*)d_in[9];
  float* out = (float*)d_out;
  float* ws  = (float*)d_ws;

  kA<<<432, 256, 0, stream>>>(J_regressor, weights, posedirs,
                              user_shape, v_template, shapedirs, ws);
  kR<<<137, 256, 0, stream>>>(ws);
  k5f<<<672, 256, 0, stream>>>(theta, delta_quat, init_quat, init_trans, ws, out);
}

// Round 19
// 140.361 us; speedup vs baseline: 1.2141x; 1.1828x over previous
//
#include <hip/hip_runtime.h>
#include <math.h>

#define B_SIZE 8192
#define NVERT 778
#define NP 135
#define NEC 416
#define KS16 16

// ---- workspace layout (floats) ----
#define OFF_JK    0         // 48
#define OFF_C1    64        // 336  (21 x 16)
#define OFF_C0    400       // 1008 (21 x 48)
#define OFF_P2    1408      // 21*135*48 = 136080
#define OFF_PFT   137488    // 135 x 8192
#define OFF_AT    1243408   // 192 x 8192
#define OFF_PP_OVER 137488  // overlays PFT/AT head (dead before pose) - 11.27 MB path
#define OFF_PP_SAFE 2816272 // after AT - needs 20.2 MB, enables merged kRk4

__device__ inline void quat2mat_dev(float qw, float qx, float qy, float qz, float* R) {
  float n = sqrtf(qw*qw + qx*qx + qy*qy + qz*qz);
  float w = qw/n, x = qx/n, y = qy/n, z = qz/n;
  float w2=w*w, x2=x*x, y2=y*y, z2=z*z;
  float wx=w*x, wy=w*y, wz=w*z, xy=x*y, xz=x*z, yz=y*z;
  R[0]=w2+x2-y2-z2; R[1]=2.f*xy-2.f*wz; R[2]=2.f*wy+2.f*xz;
  R[3]=2.f*wz+2.f*xy; R[4]=w2-x2+y2-z2; R[5]=2.f*yz-2.f*wx;
  R[6]=2.f*xz-2.f*wy; R[7]=2.f*wx+2.f*yz; R[8]=w2-x2-y2+z2;
}

__device__ inline void rodrigues_dev(float tx, float ty, float tz, float* R) {
  float ax = tx + 1e-8f, ay = ty + 1e-8f, az = tz + 1e-8f;
  float angle = sqrtf(ax*ax + ay*ay + az*az);
  float nx = tx/angle, ny = ty/angle, nz = tz/angle;
  float half = 0.5f*angle;
  float cw = cosf(half), sw = sinf(half);
  quat2mat_dev(cw, sw*nx, sw*ny, sw*nz, R);
}

__device__ inline void pose_unit(const float* __restrict__ theta,
                                 const float* __restrict__ delta_quat,
                                 const float* __restrict__ init_quat,
                                 float* __restrict__ ws,
                                 const float* jk, const float* rel,
                                 int bb, int u, int lane) {
  int b = bb*256 + lane;
  float* pfT = ws + OFF_PFT;
  float* AT  = ws + OFF_AT;
  float w1=delta_quat[b*4+0], x1=delta_quat[b*4+1], y1=delta_quat[b*4+2], z1=delta_quat[b*4+3];
  float w2=init_quat[0], x2=init_quat[1], y2=init_quat[2], z2=init_quat[3];
  float qw = w1*w2 - x1*x2 - y1*y2 - z1*z2;
  float qx = w1*x2 + x1*w2 + y1*z2 - z1*y2;
  float qy = w1*y2 - x1*z2 + y1*w2 + z1*x2;
  float qz = w1*z2 + x1*y2 - y1*x2 + z1*w2;
  float G[12];
  quat2mat_dev(qw, qx, qy, qz, G);
  G[9] = rel[0]; G[10] = rel[1]; G[11] = rel[2];
  if (u == 5) {
    #pragma unroll
    for (int c = 0; c < 3; ++c) {
      float g0 = G[c*3+0], g1 = G[c*3+1], g2 = G[c*3+2];
      AT[(size_t)(c*4+0)*B_SIZE + b] = g0;
      AT[(size_t)(c*4+1)*B_SIZE + b] = g1;
      AT[(size_t)(c*4+2)*B_SIZE + b] = g2;
      AT[(size_t)(c*4+3)*B_SIZE + b] = G[9+c] - (g0*jk[0] + g1*jk[1] + g2*jk[2]);
    }
    return;
  }
  #pragma unroll
  for (int mstep = 0; mstep < 3; ++mstep) {
    int j = 3*u + 1 + mstep;
    int i = j - 1;
    float R[9];
    rodrigues_dev(theta[b*45+3*i+0], theta[b*45+3*i+1], theta[b*45+3*i+2], R);
    pfT[(size_t)(9*i+0)*B_SIZE + b] = R[0]-1.f;
    pfT[(size_t)(9*i+1)*B_SIZE + b] = R[1];
    pfT[(size_t)(9*i+2)*B_SIZE + b] = R[2];
    pfT[(size_t)(9*i+3)*B_SIZE + b] = R[3];
    pfT[(size_t)(9*i+4)*B_SIZE + b] = R[4]-1.f;
    pfT[(size_t)(9*i+5)*B_SIZE + b] = R[5];
    pfT[(size_t)(9*i+6)*B_SIZE + b] = R[6];
    pfT[(size_t)(9*i+7)*B_SIZE + b] = R[7];
    pfT[(size_t)(9*i+8)*B_SIZE + b] = R[8]-1.f;
    float nG[12];
    const float* rj = rel + j*3;
    #pragma unroll
    for (int r3 = 0; r3 < 3; ++r3) {
      float a0 = G[r3*3+0], a1 = G[r3*3+1], a2 = G[r3*3+2];
      nG[r3*3+0] = a0*R[0] + a1*R[3] + a2*R[6];
      nG[r3*3+1] = a0*R[1] + a1*R[4] + a2*R[7];
      nG[r3*3+2] = a0*R[2] + a1*R[5] + a2*R[8];
      nG[9+r3]   = G[9+r3] + a0*rj[0] + a1*rj[1] + a2*rj[2];
    }
    #pragma unroll
    for (int k = 0; k < 12; ++k) G[k] = nG[k];
    const float* jkj = jk + j*3;
    #pragma unroll
    for (int c = 0; c < 3; ++c) {
      float g0 = G[c*3+0], g1 = G[c*3+1], g2 = G[c*3+2];
      AT[(size_t)(j*12 + c*4+0)*B_SIZE + b] = g0;
      AT[(size_t)(j*12 + c*4+1)*B_SIZE + b] = g1;
      AT[(size_t)(j*12 + c*4+2)*B_SIZE + b] = g2;
      AT[(size_t)(j*12 + c*4+3)*B_SIZE + b] = G[9+c] - (g0*jkj[0] + g1*jkj[1] + g2*jkj[2]);
    }
  }
}

__device__ inline void kr_task(float* __restrict__ ws, int pp_off, int idx) {
  if (idx >= 416*84) return;
  int ec = idx / 84, q4 = idx - ec*84;
  const float* Pp = ws + pp_off;
  float4 s = make_float4(0.f, 0.f, 0.f, 0.f);
  #pragma unroll
  for (int ks = 0; ks < KS16; ++ks) {
    float4 v = *(const float4*)&Pp[(size_t)ks*NEC*336 + ec*336 + 4*q4];
    s.x += v.x; s.y += v.y; s.z += v.z; s.w += v.w;
  }
  float sv[4] = {s.x, s.y, s.z, s.w};
  #pragma unroll
  for (int r = 0; r < 4; ++r) {
    int q2 = 4*q4 + r;
    int jj2 = q2 >> 4, jj = q2 & 15;
    if (ec < 408) {
      int c = ec / 136, pp = ec - c*136;
      if (pp < 135) ws[OFF_P2 + (size_t)(jj2*135 + pp)*48 + jj*3 + c] = sv[r];
      else          ws[OFF_C0 + jj2*48 + jj*3 + c] = sv[r];
    } else if (ec == 408) {
      ws[OFF_C1 + jj2*16 + jj] = sv[r];
    }
  }
}

// kA: blocks 0..415 = single-chunk GEMM partials -> PP; 416..431 = Jk regression. (proven)
__global__ __launch_bounds__(256) void kA(const float* __restrict__ J_regressor,
                                          const float* __restrict__ weights,
                                          const float* __restrict__ posedirs,
                                          const float* __restrict__ user_shape,
                                          const float* __restrict__ v_template,
                                          const float* __restrict__ shapedirs,
                                          float* __restrict__ ws, int pp_off) {
  int tid = threadIdx.x;
  int bid = blockIdx.x;

  if (bid >= 416) {
    int j = bid - 416;
    __shared__ float red[3*256];
    __shared__ float ush[10];
    if (tid < 10) ush[tid] = user_shape[tid];
    __syncthreads();
    float p0 = 0.f, p1 = 0.f, p2 = 0.f;
    for (int v = tid; v < NVERT; v += 256) {
      float jr = J_regressor[v*21 + j];
      #pragma unroll
      for (int c = 0; c < 3; ++c) {
        int e = 3*v + c;
        float t = v_template[e];
        #pragma unroll
        for (int s = 0; s < 10; ++s) t += ush[s]*shapedirs[s*2334 + e];
        float val = jr * t;
        if (c == 0) p0 += val; else if (c == 1) p1 += val; else p2 += val;
      }
    }
    red[0*256+tid] = p0; red[1*256+tid] = p1; red[2*256+tid] = p2;
    __syncthreads();
    for (int s = 128; s > 0; s >>= 1) {
      if (tid < s) {
        red[0*256+tid] += red[0*256+tid+s];
        red[1*256+tid] += red[1*256+tid+s];
        red[2*256+tid] += red[2*256+tid+s];
      }
      __syncthreads();
    }
    if (tid < 3) ws[OFF_JK + j*3 + tid] = red[tid*256];
    return;
  }

  __shared__ float sJR[49*21];
  __shared__ float sW [49*16];
  __shared__ float sB [64*16];
  __shared__ float ush[10];
  if (tid < 10) ush[tid] = user_shape[tid];
  int ng = bid % 26;
  int ks = bid / 26;
  int vbeg = ks*49;
  int kt = min(NVERT - vbeg, 49);
  __syncthreads();
  for (int idx = tid; idx < kt*21; idx += 256) sJR[idx] = J_regressor[vbeg*21 + idx];
  for (int idx = tid; idx < kt*16; idx += 256) sW[idx]  = weights[vbeg*16 + idx];
  for (int idx = tid; idx < 16*64; idx += 256) {
    int s = idx >> 6, iv = idx & 63;
    if (iv < kt) {
      int ec = ng*16 + s;
      float val;
      if (ec > 408) val = 0.f;
      else if (ec == 408) val = 1.f;
      else {
        int c = ec / 136, pp = ec - c*136;
        int e = 3*(vbeg+iv) + c;
        if (pp == 135) {
          float t = v_template[e];
          #pragma unroll
          for (int s0 = 0; s0 < 10; ++s0) t += ush[s0]*shapedirs[s0*2334 + e];
          val = t;
        } else {
          val = posedirs[pp*2334 + e];
        }
      }
      sB[iv*16 + s] = val;
    }
  }
  __syncthreads();
  if (tid < 168) {
    int cg2 = (tid < 84) ? 0 : 1;
    int r4  = (tid < 84) ? tid : tid - 84;
    int q2 = 4*r4;
    int j2 = q2 >> 4;
    int jb = q2 & 15;
    float acc[4][8];
    #pragma unroll
    for (int r = 0; r < 4; ++r)
      #pragma unroll
      for (int s = 0; s < 8; ++s) acc[r][s] = 0.f;
    for (int i = 0; i < kt; ++i) {
      float jr = sJR[i*21 + j2];
      float4 w4 = *(const float4*)&sW[i*16 + jb];
      float4 b0 = *(const float4*)&sB[i*16 + cg2*8];
      float4 b1 = *(const float4*)&sB[i*16 + cg2*8 + 4];
      float wv[4] = {w4.x, w4.y, w4.z, w4.w};
      #pragma unroll
      for (int r = 0; r < 4; ++r) {
        float s2 = jr * wv[r];
        acc[r][0] += s2*b0.x; acc[r][1] += s2*b0.y;
        acc[r][2] += s2*b0.z; acc[r][3] += s2*b0.w;
        acc[r][4] += s2*b1.x; acc[r][5] += s2*b1.y;
        acc[r][6] += s2*b1.z; acc[r][7] += s2*b1.w;
      }
    }
    float* Pp = ws + pp_off + (size_t)ks*NEC*336;
    #pragma unroll
    for (int s = 0; s < 8; ++s) {
      int ec = ng*16 + cg2*8 + s;
      float4 v4 = make_float4(acc[0][s], acc[1][s], acc[2][s], acc[3][s]);
      *(float4*)&Pp[ec*336 + q2] = v4;
    }
  }
}

// merged kR + k4 (PP non-overlapping). bid<137 = reduce; 137..328 = pose units.
__global__ __launch_bounds__(256) void kRk4(const float* __restrict__ theta,
                                            const float* __restrict__ delta_quat,
                                            const float* __restrict__ init_quat,
                                            float* __restrict__ ws, int pp_off) {
  int bid = blockIdx.x;
  int tid = threadIdx.x;
  if (bid < 137) {
    kr_task(ws, pp_off, bid*256 + tid);
    return;
  }
  __shared__ float jk[48], rel[48];
  if (tid < 48) {
    float v = ws[OFF_JK + tid];
    jk[tid] = v;
    int j = tid/3, c = tid - j*3;
    float r;
    if (j == 0) r = v;
    else {
      int par = (((j-1) % 3) == 0) ? 0 : (j-1);
      r = v - ws[OFF_JK + par*3 + c];
    }
    rel[tid] = r;
  }
  __syncthreads();
  int s = bid & 7;
  int t = (bid - 137) >> 3;
  int bb = s + 8*(t & 3);
  int u  = t >> 2;
  pose_unit(theta, delta_quat, init_quat, ws, jk, rel, bb, u, tid);
}

__global__ void kR_fb(float* __restrict__ ws, int pp_off) {
  kr_task(ws, pp_off, blockIdx.x*256 + threadIdx.x);
}

__global__ __launch_bounds__(256) void k4_fb(const float* __restrict__ theta,
                                             const float* __restrict__ delta_quat,
                                             const float* __restrict__ init_quat,
                                             float* __restrict__ ws) {
  int bid = blockIdx.x;
  int tid = threadIdx.x;
  __shared__ float jk[48], rel[48];
  if (tid < 48) {
    float v = ws[OFF_JK + tid];
    jk[tid] = v;
    int j = tid/3, c = tid - j*3;
    float r;
    if (j == 0) r = v;
    else {
      int par = (((j-1) % 3) == 0) ? 0 : (j-1);
      r = v - ws[OFF_JK + par*3 + c];
    }
    rel[tid] = r;
  }
  __syncthreads();
  int s = bid & 7;
  int t = bid >> 3;
  int bb = s + 8*(t & 3);
  int u  = t >> 2;
  pose_unit(theta, delta_quat, init_quat, ws, jk, rel, bb, u, tid);
}

// k5: round-15 body (proven 46.3 µs) at 1-wave granularity: 2688 blocks x 64 threads.
// Same per-wave work/mapping; finest scheduling granularity kills the 672-block
// tail imbalance (2.625 blocks/CU -> 3-vs-2 heavy-block skew). P2 via LDS-laundered
// VMEM path (in-order vmcnt -> software-pipelined, the proven-best delivery).
__global__ __launch_bounds__(64) void k5_main(const float* __restrict__ init_trans,
                                              const float* __restrict__ ws,
                                              float* __restrict__ out) {
  __shared__ int s_voff[1];
  int g = blockIdx.x;              // 0..2687 = 8 xcd * 16 * 21
  int xcd = g & 7, k = g >> 3;     // k 0..335
  int br  = ((k & 15) << 3) | xcd; // 0..127 ; all j2 of a br-range share an XCD
  int j2  = k >> 4;                // 0..20
  int tid = threadIdx.x;
  int b   = br*64 + tid;

  if (tid == 0) s_voff[0] = j2*135*12;
  __syncthreads();
  int voff = s_voff[0];            // divergent in compiler's view -> VMEM addressing

  float4 acc[12];
  const float4* c04 = (const float4*)(ws + OFF_C0 + j2*48);
  #pragma unroll
  for (int i = 0; i < 12; ++i) acc[i] = c04[i];

  const float* pfT = ws + OFF_PFT;
  const float4* P24 = (const float4*)(ws + OFF_P2) + voff;
  #pragma unroll 3
  for (int p = 0; p < NP; ++p) {
    float pf = pfT[(size_t)p*B_SIZE + b];
    const float4* Pr = P24 + p*12;
    #pragma unroll
    for (int i = 0; i < 12; ++i) {
      float4 pv = Pr[i];
      acc[i].x += pf*pv.x; acc[i].y += pf*pv.y;
      acc[i].z += pf*pv.z; acc[i].w += pf*pv.w;
    }
  }

  float m[48];
  #pragma unroll
  for (int i = 0; i < 12; ++i) {
    m[4*i+0] = acc[i].x; m[4*i+1] = acc[i].y;
    m[4*i+2] = acc[i].z; m[4*i+3] = acc[i].w;
  }

  const float* AT  = ws + OFF_AT;
  const float* c1p = ws + OFF_C1 + j2*16;
  float o0 = 0.f, o1 = 0.f, o2 = 0.f;
  #pragma unroll
  for (int j = 0; j < 16; ++j) {
    float c1 = c1p[j];
    float m0 = m[3*j+0], m1 = m[3*j+1], m2 = m[3*j+2];
    #pragma unroll
    for (int k2 = 0; k2 < 3; ++k2) {
      float a0 = AT[(size_t)(j*12 + k2*4+0)*B_SIZE + b];
      float a1 = AT[(size_t)(j*12 + k2*4+1)*B_SIZE + b];
      float a2 = AT[(size_t)(j*12 + k2*4+2)*B_SIZE + b];
      float a3 = AT[(size_t)(j*12 + k2*4+3)*B_SIZE + b];
      float r = a0*m0 + a1*m1 + a2*m2 + a3*c1;
      if (k2 == 0) o0 += r; else if (k2 == 1) o1 += r; else o2 += r;
    }
  }
  size_t ob = ((size_t)b*21 + j2)*3;
  out[ob+0] = o0 + init_trans[b*3+0];
  out[ob+1] = o1 + init_trans[b*3+1];
  out[ob+2] = o2 + init_trans[b*3+2];
}

extern "C" void kernel_launch(void* const* d_in, const int* in_sizes, int n_in,
                              void* d_out, int out_size, void* d_ws, size_t ws_size,
                              hipStream_t stream) {
  const float* theta       = (const float*)d_in[0];
  const float* delta_quat  = (const float*)d_in[1];
  const float* user_shape  = (const float*)d_in[2];
  const float* init_quat   = (const float*)d_in[3];
  const float* init_trans  = (const float*)d_in[4];
  const float* v_template  = (const float*)d_in[5];
  const float* shapedirs   = (const float*)d_in[6];
  const float* J_regressor = (const float*)d_in[7];
  const float* posedirs    = (const float*)d_in[8];
  const float* weights     = (const float*)d_in[9];
  float* out = (float*)d_out;
  float* ws  = (float*)d_ws;

  size_t need = ((size_t)OFF_PP_SAFE + (size_t)KS16*NEC*336) * 4;
  if (ws_size >= need) {
    // 3-dispatch path: PP after AT, kR+k4 merged
    kA<<<432, 256, 0, stream>>>(J_regressor, weights, posedirs,
                                user_shape, v_template, shapedirs, ws, OFF_PP_SAFE);
    kRk4<<<329, 256, 0, stream>>>(theta, delta_quat, init_quat, ws, OFF_PP_SAFE);
  } else {
    // proven 4-dispatch path: PP overlays PFT/AT (dead before pose)
    kA<<<432, 256, 0, stream>>>(J_regressor, weights, posedirs,
                                user_shape, v_template, shapedirs, ws, OFF_PP_OVER);
    kR_fb<<<137, 256, 0, stream>>>(ws, OFF_PP_OVER);
    k4_fb<<<192, 256, 0, stream>>>(theta, delta_quat, init_quat, ws);
  }
  k5_main<<<2688, 64, 0, stream>>>(init_trans, ws, out);
}

// Round 20
// 139.799 us; speedup vs baseline: 1.2190x; 1.0040x over previous
//
#include <hip/hip_runtime.h>
#include <math.h>

#define B_SIZE 8192
#define NVERT 778
#define NP 135
#define NEC 416
#define KS16 16

// ---- workspace layout (floats) ----
#define OFF_JK    0         // 48
#define OFF_C1    64        // 336  (21 x 16)
#define OFF_C0    400       // 1008 (21 x 48)
#define OFF_P2    1408      // 21*135*48 = 136080
#define OFF_PFT   137488    // 135 x 8192
#define OFF_AT    1243408   // 192 x 8192
#define OFF_PP_OVER 137488  // overlays PFT/AT head (dead before pose) - 11.27 MB path
#define OFF_PP_SAFE 2816272 // after AT - needs 20.2 MB, enables merged kRk4

__device__ inline void quat2mat_dev(float qw, float qx, float qy, float qz, float* R) {
  float n = sqrtf(qw*qw + qx*qx + qy*qy + qz*qz);
  float w = qw/n, x = qx/n, y = qy/n, z = qz/n;
  float w2=w*w, x2=x*x, y2=y*y, z2=z*z;
  float wx=w*x, wy=w*y, wz=w*z, xy=x*y, xz=x*z, yz=y*z;
  R[0]=w2+x2-y2-z2; R[1]=2.f*xy-2.f*wz; R[2]=2.f*wy+2.f*xz;
  R[3]=2.f*wz+2.f*xy; R[4]=w2-x2+y2-z2; R[5]=2.f*yz-2.f*wx;
  R[6]=2.f*xz-2.f*wy; R[7]=2.f*wx+2.f*yz; R[8]=w2-x2-y2+z2;
}

__device__ inline void rodrigues_dev(float tx, float ty, float tz, float* R) {
  float ax = tx + 1e-8f, ay = ty + 1e-8f, az = tz + 1e-8f;
  float angle = sqrtf(ax*ax + ay*ay + az*az);
  float nx = tx/angle, ny = ty/angle, nz = tz/angle;
  float half = 0.5f*angle;
  float cw = cosf(half), sw = sinf(half);
  quat2mat_dev(cw, sw*nx, sw*ny, sw*nz, R);
}

__device__ inline void pose_unit(const float* __restrict__ theta,
                                 const float* __restrict__ delta_quat,
                                 const float* __restrict__ init_quat,
                                 float* __restrict__ ws,
                                 const float* jk, const float* rel,
                                 int bb, int u, int lane) {
  int b = bb*256 + lane;
  float* pfT = ws + OFF_PFT;
  float* AT  = ws + OFF_AT;
  float w1=delta_quat[b*4+0], x1=delta_quat[b*4+1], y1=delta_quat[b*4+2], z1=delta_quat[b*4+3];
  float w2=init_quat[0], x2=init_quat[1], y2=init_quat[2], z2=init_quat[3];
  float qw = w1*w2 - x1*x2 - y1*y2 - z1*z2;
  float qx = w1*x2 + x1*w2 + y1*z2 - z1*y2;
  float qy = w1*y2 - x1*z2 + y1*w2 + z1*x2;
  float qz = w1*z2 + x1*y2 - y1*x2 + z1*w2;
  float G[12];
  quat2mat_dev(qw, qx, qy, qz, G);
  G[9] = rel[0]; G[10] = rel[1]; G[11] = rel[2];
  if (u == 5) {
    #pragma unroll
    for (int c = 0; c < 3; ++c) {
      float g0 = G[c*3+0], g1 = G[c*3+1], g2 = G[c*3+2];
      AT[(size_t)(c*4+0)*B_SIZE + b] = g0;
      AT[(size_t)(c*4+1)*B_SIZE + b] = g1;
      AT[(size_t)(c*4+2)*B_SIZE + b] = g2;
      AT[(size_t)(c*4+3)*B_SIZE + b] = G[9+c] - (g0*jk[0] + g1*jk[1] + g2*jk[2]);
    }
    return;
  }
  #pragma unroll
  for (int mstep = 0; mstep < 3; ++mstep) {
    int j = 3*u + 1 + mstep;
    int i = j - 1;
    float R[9];
    rodrigues_dev(theta[b*45+3*i+0], theta[b*45+3*i+1], theta[b*45+3*i+2], R);
    pfT[(size_t)(9*i+0)*B_SIZE + b] = R[0]-1.f;
    pfT[(size_t)(9*i+1)*B_SIZE + b] = R[1];
    pfT[(size_t)(9*i+2)*B_SIZE + b] = R[2];
    pfT[(size_t)(9*i+3)*B_SIZE + b] = R[3];
    pfT[(size_t)(9*i+4)*B_SIZE + b] = R[4]-1.f;
    pfT[(size_t)(9*i+5)*B_SIZE + b] = R[5];
    pfT[(size_t)(9*i+6)*B_SIZE + b] = R[6];
    pfT[(size_t)(9*i+7)*B_SIZE + b] = R[7];
    pfT[(size_t)(9*i+8)*B_SIZE + b] = R[8]-1.f;
    float nG[12];
    const float* rj = rel + j*3;
    #pragma unroll
    for (int r3 = 0; r3 < 3; ++r3) {
      float a0 = G[r3*3+0], a1 = G[r3*3+1], a2 = G[r3*3+2];
      nG[r3*3+0] = a0*R[0] + a1*R[3] + a2*R[6];
      nG[r3*3+1] = a0*R[1] + a1*R[4] + a2*R[7];
      nG[r3*3+2] = a0*R[2] + a1*R[5] + a2*R[8];
      nG[9+r3]   = G[9+r3] + a0*rj[0] + a1*rj[1] + a2*rj[2];
    }
    #pragma unroll
    for (int k = 0; k < 12; ++k) G[k] = nG[k];
    const float* jkj = jk + j*3;
    #pragma unroll
    for (int c = 0; c < 3; ++c) {
      float g0 = G[c*3+0], g1 = G[c*3+1], g2 = G[c*3+2];
      AT[(size_t)(j*12 + c*4+0)*B_SIZE + b] = g0;
      AT[(size_t)(j*12 + c*4+1)*B_SIZE + b] = g1;
      AT[(size_t)(j*12 + c*4+2)*B_SIZE + b] = g2;
      AT[(size_t)(j*12 + c*4+3)*B_SIZE + b] = G[9+c] - (g0*jkj[0] + g1*jkj[1] + g2*jkj[2]);
    }
  }
}

__device__ inline void kr_task(float* __restrict__ ws, int pp_off, int idx) {
  if (idx >= 416*84) return;
  int ec = idx / 84, q4 = idx - ec*84;
  const float* Pp = ws + pp_off;
  float4 s = make_float4(0.f, 0.f, 0.f, 0.f);
  #pragma unroll
  for (int ks = 0; ks < KS16; ++ks) {
    float4 v = *(const float4*)&Pp[(size_t)ks*NEC*336 + ec*336 + 4*q4];
    s.x += v.x; s.y += v.y; s.z += v.z; s.w += v.w;
  }
  float sv[4] = {s.x, s.y, s.z, s.w};
  #pragma unroll
  for (int r = 0; r < 4; ++r) {
    int q2 = 4*q4 + r;
    int jj2 = q2 >> 4, jj = q2 & 15;
    if (ec < 408) {
      int c = ec / 136, pp = ec - c*136;
      if (pp < 135) ws[OFF_P2 + (size_t)(jj2*135 + pp)*48 + jj*3 + c] = sv[r];
      else          ws[OFF_C0 + jj2*48 + jj*3 + c] = sv[r];
    } else if (ec == 408) {
      ws[OFF_C1 + jj2*16 + jj] = sv[r];
    }
  }
}

// kA: blocks 0..415 = single-chunk GEMM partials -> PP; 416..431 = Jk regression. (proven)
__global__ __launch_bounds__(256) void kA(const float* __restrict__ J_regressor,
                                          const float* __restrict__ weights,
                                          const float* __restrict__ posedirs,
                                          const float* __restrict__ user_shape,
                                          const float* __restrict__ v_template,
                                          const float* __restrict__ shapedirs,
                                          float* __restrict__ ws, int pp_off) {
  int tid = threadIdx.x;
  int bid = blockIdx.x;

  if (bid >= 416) {
    int j = bid - 416;
    __shared__ float red[3*256];
    __shared__ float ush[10];
    if (tid < 10) ush[tid] = user_shape[tid];
    __syncthreads();
    float p0 = 0.f, p1 = 0.f, p2 = 0.f;
    for (int v = tid; v < NVERT; v += 256) {
      float jr = J_regressor[v*21 + j];
      #pragma unroll
      for (int c = 0; c < 3; ++c) {
        int e = 3*v + c;
        float t = v_template[e];
        #pragma unroll
        for (int s = 0; s < 10; ++s) t += ush[s]*shapedirs[s*2334 + e];
        float val = jr * t;
        if (c == 0) p0 += val; else if (c == 1) p1 += val; else p2 += val;
      }
    }
    red[0*256+tid] = p0; red[1*256+tid] = p1; red[2*256+tid] = p2;
    __syncthreads();
    for (int s = 128; s > 0; s >>= 1) {
      if (tid < s) {
        red[0*256+tid] += red[0*256+tid+s];
        red[1*256+tid] += red[1*256+tid+s];
        red[2*256+tid] += red[2*256+tid+s];
      }
      __syncthreads();
    }
    if (tid < 3) ws[OFF_JK + j*3 + tid] = red[tid*256];
    return;
  }

  __shared__ float sJR[49*21];
  __shared__ float sW [49*16];
  __shared__ float sB [64*16];
  __shared__ float ush[10];
  if (tid < 10) ush[tid] = user_shape[tid];
  int ng = bid % 26;
  int ks = bid / 26;
  int vbeg = ks*49;
  int kt = min(NVERT - vbeg, 49);
  __syncthreads();
  for (int idx = tid; idx < kt*21; idx += 256) sJR[idx] = J_regressor[vbeg*21 + idx];
  for (int idx = tid; idx < kt*16; idx += 256) sW[idx]  = weights[vbeg*16 + idx];
  for (int idx = tid; idx < 16*64; idx += 256) {
    int s = idx >> 6, iv = idx & 63;
    if (iv < kt) {
      int ec = ng*16 + s;
      float val;
      if (ec > 408) val = 0.f;
      else if (ec == 408) val = 1.f;
      else {
        int c = ec / 136, pp = ec - c*136;
        int e = 3*(vbeg+iv) + c;
        if (pp == 135) {
          float t = v_template[e];
          #pragma unroll
          for (int s0 = 0; s0 < 10; ++s0) t += ush[s0]*shapedirs[s0*2334 + e];
          val = t;
        } else {
          val = posedirs[pp*2334 + e];
        }
      }
      sB[iv*16 + s] = val;
    }
  }
  __syncthreads();
  if (tid < 168) {
    int cg2 = (tid < 84) ? 0 : 1;
    int r4  = (tid < 84) ? tid : tid - 84;
    int q2 = 4*r4;
    int j2 = q2 >> 4;
    int jb = q2 & 15;
    float acc[4][8];
    #pragma unroll
    for (int r = 0; r < 4; ++r)
      #pragma unroll
      for (int s = 0; s < 8; ++s) acc[r][s] = 0.f;
    for (int i = 0; i < kt; ++i) {
      float jr = sJR[i*21 + j2];
      float4 w4 = *(const float4*)&sW[i*16 + jb];
      float4 b0 = *(const float4*)&sB[i*16 + cg2*8];
      float4 b1 = *(const float4*)&sB[i*16 + cg2*8 + 4];
      float wv[4] = {w4.x, w4.y, w4.z, w4.w};
      #pragma unroll
      for (int r = 0; r < 4; ++r) {
        float s2 = jr * wv[r];
        acc[r][0] += s2*b0.x; acc[r][1] += s2*b0.y;
        acc[r][2] += s2*b0.z; acc[r][3] += s2*b0.w;
        acc[r][4] += s2*b1.x; acc[r][5] += s2*b1.y;
        acc[r][6] += s2*b1.z; acc[r][7] += s2*b1.w;
      }
    }
    float* Pp = ws + pp_off + (size_t)ks*NEC*336;
    #pragma unroll
    for (int s = 0; s < 8; ++s) {
      int ec = ng*16 + cg2*8 + s;
      float4 v4 = make_float4(acc[0][s], acc[1][s], acc[2][s], acc[3][s]);
      *(float4*)&Pp[ec*336 + q2] = v4;
    }
  }
}

// merged kR + k4 (PP non-overlapping). bid<137 = reduce; 137..328 = pose units. (proven)
__global__ __launch_bounds__(256) void kRk4(const float* __restrict__ theta,
                                            const float* __restrict__ delta_quat,
                                            const float* __restrict__ init_quat,
                                            float* __restrict__ ws, int pp_off) {
  int bid = blockIdx.x;
  int tid = threadIdx.x;
  if (bid < 137) {
    kr_task(ws, pp_off, bid*256 + tid);
    return;
  }
  __shared__ float jk[48], rel[48];
  if (tid < 48) {
    float v = ws[OFF_JK + tid];
    jk[tid] = v;
    int j = tid/3, c = tid - j*3;
    float r;
    if (j == 0) r = v;
    else {
      int par = (((j-1) % 3) == 0) ? 0 : (j-1);
      r = v - ws[OFF_JK + par*3 + c];
    }
    rel[tid] = r;
  }
  __syncthreads();
  int s = bid & 7;
  int t = (bid - 137) >> 3;
  int bb = s + 8*(t & 3);
  int u  = t >> 2;
  pose_unit(theta, delta_quat, init_quat, ws, jk, rel, bb, u, tid);
}

__global__ void kR_fb(float* __restrict__ ws, int pp_off) {
  kr_task(ws, pp_off, blockIdx.x*256 + threadIdx.x);
}

__global__ __launch_bounds__(256) void k4_fb(const float* __restrict__ theta,
                                             const float* __restrict__ delta_quat,
                                             const float* __restrict__ init_quat,
                                             float* __restrict__ ws) {
  int bid = blockIdx.x;
  int tid = threadIdx.x;
  __shared__ float jk[48], rel[48];
  if (tid < 48) {
    float v = ws[OFF_JK + tid];
    jk[tid] = v;
    int j = tid/3, c = tid - j*3;
    float r;
    if (j == 0) r = v;
    else {
      int par = (((j-1) % 3) == 0) ? 0 : (j-1);
      r = v - ws[OFF_JK + par*3 + c];
    }
    rel[tid] = r;
  }
  __syncthreads();
  int s = bid & 7;
  int t = bid >> 3;
  int bb = s + 8*(t & 3);
  int u  = t >> 2;
  pose_unit(theta, delta_quat, init_quat, ws, jk, rel, bb, u, tid);
}

// k5: EXACT round-15 configuration (proven 46.3 µs, FETCH 10.3 MB): 672 blocks x 256,
// XCD-swizzled, P2 via LDS-laundered VMEM path (in-order vmcnt -> pipelined float4 loads).
// 256-thread blocks maximize intra-block L1 reuse of AT/pfT rows (64-thread variant
// regressed to 48.9 µs / 12.3 MB FETCH — round 19).
__global__ __launch_bounds__(256) void k5_main(const float* __restrict__ init_trans,
                                               const float* __restrict__ ws,
                                               float* __restrict__ out) {
  __shared__ int s_voff[1];
  int g = blockIdx.x;
  int xcd = g & 7, k = g >> 3;
  int br  = ((k & 3) << 3) | xcd;
  int j2  = k >> 2;
  int tid = threadIdx.x;
  int b   = br*256 + tid;

  if (tid == 0) s_voff[0] = j2*135*12;
  __syncthreads();
  int voff = s_voff[0];            // divergent in compiler's view -> VMEM addressing

  float4 acc[12];
  const float4* c04 = (const float4*)(ws + OFF_C0 + j2*48);
  #pragma unroll
  for (int i = 0; i < 12; ++i) acc[i] = c04[i];

  const float* pfT = ws + OFF_PFT;
  const float4* P24 = (const float4*)(ws + OFF_P2) + voff;
  #pragma unroll 3
  for (int p = 0; p < NP; ++p) {
    float pf = pfT[(size_t)p*B_SIZE + b];
    const float4* Pr = P24 + p*12;
    #pragma unroll
    for (int i = 0; i < 12; ++i) {
      float4 pv = Pr[i];
      acc[i].x += pf*pv.x; acc[i].y += pf*pv.y;
      acc[i].z += pf*pv.z; acc[i].w += pf*pv.w;
    }
  }

  float m[48];
  #pragma unroll
  for (int i = 0; i < 12; ++i) {
    m[4*i+0] = acc[i].x; m[4*i+1] = acc[i].y;
    m[4*i+2] = acc[i].z; m[4*i+3] = acc[i].w;
  }

  const float* AT  = ws + OFF_AT;
  const float* c1p = ws + OFF_C1 + j2*16;
  float o0 = 0.f, o1 = 0.f, o2 = 0.f;
  #pragma unroll
  for (int j = 0; j < 16; ++j) {
    float c1 = c1p[j];
    float m0 = m[3*j+0], m1 = m[3*j+1], m2 = m[3*j+2];
    #pragma unroll
    for (int k2 = 0; k2 < 3; ++k2) {
      float a0 = AT[(size_t)(j*12 + k2*4+0)*B_SIZE + b];
      float a1 = AT[(size_t)(j*12 + k2*4+1)*B_SIZE + b];
      float a2 = AT[(size_t)(j*12 + k2*4+2)*B_SIZE + b];
      float a3 = AT[(size_t)(j*12 + k2*4+3)*B_SIZE + b];
      float r = a0*m0 + a1*m1 + a2*m2 + a3*c1;
      if (k2 == 0) o0 += r; else if (k2 == 1) o1 += r; else o2 += r;
    }
  }
  size_t ob = ((size_t)b*21 + j2)*3;
  out[ob+0] = o0 + init_trans[b*3+0];
  out[ob+1] = o1 + init_trans[b*3+1];
  out[ob+2] = o2 + init_trans[b*3+2];
}

extern "C" void kernel_launch(void* const* d_in, const int* in_sizes, int n_in,
                              void* d_out, int out_size, void* d_ws, size_t ws_size,
                              hipStream_t stream) {
  const float* theta       = (const float*)d_in[0];
  const float* delta_quat  = (const float*)d_in[1];
  const float* user_shape  = (const float*)d_in[2];
  const float* init_quat   = (const float*)d_in[3];
  const float* init_trans  = (const float*)d_in[4];
  const float* v_template  = (const float*)d_in[5];
  const float* shapedirs   = (const float*)d_in[6];
  const float* J_regressor = (const float*)d_in[7];
  const float* posedirs    = (const float*)d_in[8];
  const float* weights     = (const float*)d_in[9];
  float* out = (float*)d_out;
  float* ws  = (float*)d_ws;

  size_t need = ((size_t)OFF_PP_SAFE + (size_t)KS16*NEC*336) * 4;
  if (ws_size >= need) {
    // 3-dispatch path: PP after AT, kR+k4 merged (proven -4.4 µs vs 4-dispatch)
    kA<<<432, 256, 0, stream>>>(J_regressor, weights, posedirs,
                                user_shape, v_template, shapedirs, ws, OFF_PP_SAFE);
    kRk4<<<329, 256, 0, stream>>>(theta, delta_quat, init_quat, ws, OFF_PP_SAFE);
  } else {
    // proven 4-dispatch path: PP overlays PFT/AT (dead before pose)
    kA<<<432, 256, 0, stream>>>(J_regressor, weights, posedirs,
                                user_shape, v_template, shapedirs, ws, OFF_PP_OVER);
    kR_fb<<<137, 256, 0, stream>>>(ws, OFF_PP_OVER);
    k4_fb<<<192, 256, 0, stream>>>(theta, delta_quat, init_quat, ws);
  }
  k5_main<<<672, 256, 0, stream>>>(init_trans, ws, out);
}